// Round 9
// baseline (357.319 us; speedup 1.0000x reference)
//
#include <hip/hip_runtime.h>
#include <hip/hip_bf16.h>

#define E_  8
#define T_  4096
#define DH_ 2048
#define DI_ 5632
#define R_  128
#define TILE_ 64
#define NT_ 72                  // T/64 + E  (worst-case padded tiles)
#define TPMAX_ (NT_*TILE_)      // 4608

// k_mega block layout
#define CVT_BLOCKS_ 13312       // 13,631,488 floats (gB+uB+dB) / 1024
#define FOLD_BLOCKS_ 608        // 76 chunks x 8 experts
#define ROUTE_BLK_ (CVT_BLOCKS_ + FOLD_BLOCKS_)   // 13920
#define MEGA_GRID_ (ROUTE_BLK_ + 1)               // 13921

typedef short bf16x8 __attribute__((ext_vector_type(8)));
typedef short bf16x4 __attribute__((ext_vector_type(4)));
typedef float f32x4 __attribute__((ext_vector_type(4)));

#define MFMA(a, b, c) __builtin_amdgcn_mfma_f32_16x16x32_bf16((a), (b), (c), 0, 0, 0)

// LDS-only barrier: orders DS ops (lgkmcnt) without draining in-flight global
// loads (vmcnt). stage2's only cross-wave state is LDS. (T4 discipline.)
#define BAR_LDS() asm volatile("s_waitcnt lgkmcnt(0)\n\ts_barrier" ::: "memory")

__device__ __forceinline__ unsigned short f2bf(float f) {
  union { float f; unsigned u; } v; v.f = f;
  return (unsigned short)((v.u + 0x7fffu + ((v.u >> 16) & 1u)) >> 16);
}

__device__ __forceinline__ bf16x8 cvt8(float4 a, float4 b) {
  bf16x8 o;
  o[0] = (short)f2bf(a.x); o[1] = (short)f2bf(a.y);
  o[2] = (short)f2bf(a.z); o[3] = (short)f2bf(a.w);
  o[4] = (short)f2bf(b.x); o[5] = (short)f2bf(b.y);
  o[6] = (short)f2bf(b.z); o[7] = (short)f2bf(b.w);
  return o;
}

__device__ __forceinline__ int tile_expert(int s0, const int* off) {
  int e = 0;
#pragma unroll
  for (int q = 1; q < E_; q++) if (s0 >= off[q]) e = q;
  return e;
}

// XCD-chunked tile swizzle (locality only, no correctness dependence).
// gridDim.x == NT_ == 72 == 8*9 and linear id = bx + 72*k, so XCD = bx%8:
// each XCD owns 9 contiguous tiles -> ~one expert's weight panel per XCD L2.
// Proven: stage2 FETCH 137.6 MB -> 30.0 MB.
__device__ __forceinline__ int tile_remap(int bx) {
  return (bx & 7) * (NT_ / 8) + (bx >> 3);
}

// ---- MEGA kernel: [cvt B-matrices] + [fold C into A] + [route] in ONE launch.
__global__ __launch_bounds__(256) void k_mega(
    const float* __restrict__ gB, const float* __restrict__ uB,
    const float* __restrict__ dB,
    const float* __restrict__ gC, const float* __restrict__ uC,
    const float* __restrict__ dC,
    const float* __restrict__ gA, const float* __restrict__ uA,
    const float* __restrict__ dA,
    short* __restrict__ gBb, short* __restrict__ uBb, short* __restrict__ dBb,
    short* __restrict__ gCAb, short* __restrict__ uCAb, short* __restrict__ dCAb,
    const int* __restrict__ idx, int* __restrict__ off, int* __restrict__ tok)
{
  const int blk = blockIdx.x;
  const int tid = threadIdx.x;

  if (blk < CVT_BLOCKS_) {   // ---- B-matrix fp32 -> bf16
    long i = (long)(blk * 256 + tid) * 4;
    const float* s; short* d;
    if      (i <  5767168) { s = gB; d = gBb; }
    else if (i < 11534336) { s = uB; d = uBb; i -= 5767168; }
    else                   { s = dB; d = dBb; i -= 11534336; }
    float4 v = *(const float4*)(s + i);
    bf16x4 o;
    o[0] = (short)f2bf(v.x); o[1] = (short)f2bf(v.y);
    o[2] = (short)f2bf(v.z); o[3] = (short)f2bf(v.w);
    *(bf16x4*)(d + i) = o;
    return;
  }

  if (blk == ROUTE_BLK_) {   // ---- routing: prefill tok=-1, count, offsets, scatter
    __shared__ int cnt_[E_], cur_[E_], offs_[E_ + 1];
    for (int p = tid; p < TPMAX_; p += 256) tok[p] = -1;
    if (tid < E_) cnt_[tid] = 0;
    __syncthreads();
    for (int t = tid; t < T_; t += 256) atomicAdd(&cnt_[idx[t]], 1);
    __syncthreads();
    if (tid == 0) {
      int a = 0;
      for (int e = 0; e < E_; e++) {
        offs_[e] = a; cur_[e] = a;
        a += ((cnt_[e] + TILE_ - 1) / TILE_) * TILE_;
      }
      offs_[E_] = a;
    }
    __syncthreads();
    if (tid <= E_) off[tid] = offs_[tid];
    for (int t = tid; t < T_; t += 256) {
      int p = atomicAdd(&cur_[idx[t]], 1);
      tok[p] = t;
    }
    return;
  }

  // ---- fold: CA_e = C @ A_e, bf16 out, same layout as A.
  const int f = blk - CVT_BLOCKS_;
  const int e = f / 76;
  const int c = f % 76;
  const float* A; const float* C; short* O; int D, d0;
  if (c < 16)      { A = gA + (size_t)e * R_ * DH_; C = gC; O = gCAb + (size_t)e * R_ * DH_; D = DH_; d0 = c * 128; }
  else if (c < 32) { A = uA + (size_t)e * R_ * DH_; C = uC; O = uCAb + (size_t)e * R_ * DH_; D = DH_; d0 = (c - 16) * 128; }
  else             { A = dA + (size_t)e * R_ * DI_; C = dC; O = dCAb + (size_t)e * R_ * DI_; D = DI_; d0 = (c - 32) * 128; }

  __shared__ short ATs[128][136];   // ATs[d_local][r] = A[r][d0+d_local] (bf16)
  {
    const int s = tid >> 1, h = (tid & 1) * 64;
    const float* ap = A + (size_t)s * D + d0 + h;
#pragma unroll
    for (int q = 0; q < 16; q++) {
      float4 v = *(const float4*)(ap + q * 4);
      ATs[h + q * 4 + 0][s] = (short)f2bf(v.x);
      ATs[h + q * 4 + 1][s] = (short)f2bf(v.y);
      ATs[h + q * 4 + 2][s] = (short)f2bf(v.z);
      ATs[h + q * 4 + 3][s] = (short)f2bf(v.w);
    }
  }
  __syncthreads();

  const int lane = tid & 63, wv = tid >> 6;
  const int col = lane & 15, quad = lane >> 4;
  f32x4 acc[8][2] = {};
#pragma unroll
  for (int kk = 0; kk < 4; kk++) {
    bf16x8 b[2];
#pragma unroll
    for (int nl = 0; nl < 2; nl++)
      b[nl] = *(const bf16x8*)&ATs[(wv * 2 + nl) * 16 + col][kk * 32 + quad * 8];
#pragma unroll
    for (int m = 0; m < 8; m++) {
      const float* cp = C + (size_t)(m * 16 + col) * R_ + kk * 32 + quad * 8;
      float4 c0 = *(const float4*)cp;
      float4 c1 = *(const float4*)(cp + 4);
      bf16x8 a = cvt8(c0, c1);
      acc[m][0] = MFMA(a, b[0], acc[m][0]);
      acc[m][1] = MFMA(a, b[1], acc[m][1]);
    }
  }
#pragma unroll
  for (int m = 0; m < 8; m++)
#pragma unroll
    for (int nl = 0; nl < 2; nl++)
#pragma unroll
      for (int r = 0; r < 4; r++)
        O[(size_t)(m * 16 + quad * 4 + r) * D + d0 + (wv * 2 + nl) * 16 + col] =
            (short)f2bf(acc[m][nl][r]);
}

// Gather x rows into tile order, fp32 -> bf16 (zeros for pad rows)
__global__ __launch_bounds__(256) void k_gather(
    const float* __restrict__ x, const int* __restrict__ tok,
    short* __restrict__ Xb)
{
  const int p = blockIdx.x;
  const int t = tok[p];
  const int c = threadIdx.x * 8;
  bf16x8 o;
  if (t >= 0) {
    float4 v0 = *(const float4*)(x + (size_t)t * DH_ + c);
    float4 v1 = *(const float4*)(x + (size_t)t * DH_ + c + 4);
    o = cvt8(v0, v1);
  } else {
    o = (bf16x8){0, 0, 0, 0, 0, 0, 0, 0};
  }
  *(bf16x8*)(Xb + (size_t)p * DH_ + c) = o;
}

// Stage 1 (full-K, no atomics): Hg/Hu = Xb @ CA_e^T written bf16 directly.
// Grid (NT_, 2y, 2 token-halves) = 288 blocks; block = 32 tokens x 128 cols
// x K=2048. Per wave: 2m x 2nl x 2 K-parity accumulators = 8 independent
// MFMA chains (R3-proven ILP; R5 proved 2 chains is fatal). The K-parity
// split is a trivial fp32 reassociation of the same sum.
__global__ __launch_bounds__(256) void k_stage1(
    const short* __restrict__ Xb,
    const short* __restrict__ gCAb, const short* __restrict__ uCAb,
    const int* __restrict__ off,
    short* __restrict__ Hgb, short* __restrict__ Hub)
{
  const int tile0 = tile_remap(blockIdx.x) * TILE_;
  if (tile0 >= off[E_]) return;
  const int e = tile_expert(tile0, off);
  const int y = blockIdx.y;
  const int hs = tile0 + blockIdx.z * 32;   // 32-token half
  const short* CA = (y ? uCAb : gCAb) + (size_t)e * R_ * DH_;
  short* H = y ? Hub : Hgb;

  const int tid = threadIdx.x;
  const int lane = tid & 63, wv = tid >> 6;
  const int col = lane & 15, quad = lane >> 4;

  const short* xb = Xb + (size_t)(hs + col) * DH_ + quad * 8;
  const short* cb = CA + (size_t)(wv * 32 + col) * DH_ + quad * 8;

  f32x4 accE[2][2] = {}, accO[2][2] = {};
#pragma unroll 2
  for (int k0 = 0; k0 < DH_; k0 += 64) {
    bf16x8 b0E = *(const bf16x8*)(cb + k0);
    bf16x8 b1E = *(const bf16x8*)(cb + (size_t)16 * DH_ + k0);
    bf16x8 b0O = *(const bf16x8*)(cb + k0 + 32);
    bf16x8 b1O = *(const bf16x8*)(cb + (size_t)16 * DH_ + k0 + 32);
#pragma unroll
    for (int m = 0; m < 2; m++) {
      bf16x8 xE = *(const bf16x8*)(xb + (size_t)m * 16 * DH_ + k0);
      bf16x8 xO = *(const bf16x8*)(xb + (size_t)m * 16 * DH_ + k0 + 32);
      accE[m][0] = MFMA(xE, b0E, accE[m][0]);
      accE[m][1] = MFMA(xE, b1E, accE[m][1]);
      accO[m][0] = MFMA(xO, b0O, accO[m][0]);
      accO[m][1] = MFMA(xO, b1O, accO[m][1]);
    }
  }
#pragma unroll
  for (int m = 0; m < 2; m++)
#pragma unroll
    for (int nl = 0; nl < 2; nl++) {
      f32x4 s = accE[m][nl] + accO[m][nl];
#pragma unroll
      for (int r = 0; r < 4; r++)
        H[(size_t)(hs + m * 16 + quad * 4 + r) * R_ + wv * 32 + nl * 16 + col] =
            (short)f2bf(s[r]);
    }
}

// Stage 2 (64-token tiles): G/U B-proj, silu-mul, down-CA partial accumulate.
// bf16 LDS staging (proven fast); LDS-only barriers; rcp silu; setprio.
__global__ __launch_bounds__(256) void k_stage2(
    const short* __restrict__ Hgb, const short* __restrict__ Hub,
    const short* __restrict__ gBb, const short* __restrict__ uBb,
    const short* __restrict__ dCAb,
    const int* __restrict__ off, float* __restrict__ Hd1)
{
  const int s0 = tile_remap(blockIdx.x) * TILE_;
  if (s0 >= off[E_]) return;
  const int e = tile_expert(s0, off);
  const int i0 = blockIdx.y * 512;
  const short* Bg = gBb + (size_t)e * DI_ * R_;
  const short* Bu = uBb + (size_t)e * DI_ * R_;
  const short* Ad = dCAb + (size_t)e * R_ * DI_;

  __shared__ short hgs[64][136];
  __shared__ short hus[64][136];
  __shared__ short ZT[64][136];

  const int tid = threadIdx.x;
  const int lane = tid & 63, wv = tid >> 6;
  const int col = lane & 15, quad = lane >> 4;

  // stage Hg/Hu tile into LDS (4 threads/row, 32 shorts each)
  {
    const int row = tid >> 2, seg = (tid & 3) * 32;
    const short* pg = Hgb + (size_t)(s0 + row) * R_ + seg;
    const short* pu = Hub + (size_t)(s0 + row) * R_ + seg;
#pragma unroll
    for (int q = 0; q < 4; q++) {
      *(bf16x8*)&hgs[row][seg + q * 8] = *(const bf16x8*)(pg + q * 8);
      *(bf16x8*)&hus[row][seg + q * 8] = *(const bf16x8*)(pu + q * 8);
    }
  }
  BAR_LDS();   // hgs/hus ds_writes visible; global loads unaffected

  f32x4 dacc[4][2] = {};

  for (int sc = 0; sc < 4; sc++) {
    const int ib = i0 + sc * 128;
    f32x4 gacc[4][2] = {}, uacc[4][2] = {};
    __builtin_amdgcn_s_setprio(1);
#pragma unroll
    for (int kk = 0; kk < 4; kk++) {
      bf16x8 bg[2], bu[2];
#pragma unroll
      for (int nl = 0; nl < 2; nl++) {
        size_t bo = (size_t)(ib + (wv * 2 + nl) * 16 + col) * R_ + kk * 32 + quad * 8;
        bg[nl] = *(const bf16x8*)(Bg + bo);
        bu[nl] = *(const bf16x8*)(Bu + bo);
      }
#pragma unroll
      for (int m = 0; m < 4; m++) {
        bf16x8 ag = *(const bf16x8*)&hgs[m * 16 + col][kk * 32 + quad * 8];
        bf16x8 au = *(const bf16x8*)&hus[m * 16 + col][kk * 32 + quad * 8];
#pragma unroll
        for (int nl = 0; nl < 2; nl++) {
          gacc[m][nl] = MFMA(ag, bg[nl], gacc[m][nl]);
          uacc[m][nl] = MFMA(au, bu[nl], uacc[m][nl]);
        }
      }
    }
    __builtin_amdgcn_s_setprio(0);
    BAR_LDS();   // previous sub-chunk's ZT ds_reads complete (WAR)
#pragma unroll
    for (int m = 0; m < 4; m++)
#pragma unroll
      for (int nl = 0; nl < 2; nl++)
#pragma unroll
        for (int r = 0; r < 4; r++) {
          float g = gacc[m][nl][r];
          float z = g * __builtin_amdgcn_rcpf(1.0f + __expf(-g)) * uacc[m][nl][r];
          ZT[m * 16 + quad * 4 + r][(wv * 2 + nl) * 16 + col] = (short)f2bf(z);
        }
    BAR_LDS();   // ZT ds_writes visible (RAW)
    __builtin_amdgcn_s_setprio(1);
#pragma unroll
    for (int kk2 = 0; kk2 < 4; kk2++) {
      bf16x8 ba[2];
#pragma unroll
      for (int nl = 0; nl < 2; nl++)
        ba[nl] = *(const bf16x8*)(Ad + (size_t)((wv * 2 + nl) * 16 + col) * DI_ +
                                  ib + kk2 * 32 + quad * 8);
#pragma unroll
      for (int m = 0; m < 4; m++) {
        bf16x8 za = *(const bf16x8*)&ZT[m * 16 + col][kk2 * 32 + quad * 8];
        dacc[m][0] = MFMA(za, ba[0], dacc[m][0]);
        dacc[m][1] = MFMA(za, ba[1], dacc[m][1]);
      }
    }
    __builtin_amdgcn_s_setprio(0);
  }
#pragma unroll
  for (int m = 0; m < 4; m++)
#pragma unroll
    for (int nl = 0; nl < 2; nl++)
#pragma unroll
      for (int r = 0; r < 4; r++)
        atomicAdd(&Hd1[(size_t)(s0 + m * 16 + quad * 4 + r) * R_ + (wv * 2 + nl) * 16 + col],
                  dacc[m][nl][r]);
}

// Stage 3 (single phase): out = cvt_bf16(Hd1) @ dB^T + bias.
__global__ __launch_bounds__(256) void k_stage3(
    const float* __restrict__ Hd1,
    const short* __restrict__ dBb, const float* __restrict__ dbias,
    const int* __restrict__ off, const int* __restrict__ tok,
    float* __restrict__ out)
{
  const int s0 = tile_remap(blockIdx.x) * TILE_;
  if (s0 >= off[E_]) return;
  const int e = tile_expert(s0, off);
  const int d0 = blockIdx.y * 256;

  const int tid = threadIdx.x;
  const int lane = tid & 63, wv = tid >> 6;
  const int col = lane & 15, quad = lane >> 4;

  f32x4 acc3[4][4] = {};
#pragma unroll
  for (int kk = 0; kk < 4; kk++) {
    bf16x8 b[4];
#pragma unroll
    for (int nl = 0; nl < 4; nl++)
      b[nl] = *(const bf16x8*)(dBb + (size_t)e * DH_ * R_ +
                               (size_t)(d0 + (wv * 4 + nl) * 16 + col) * R_ +
                               kk * 32 + quad * 8);
#pragma unroll
    for (int m = 0; m < 4; m++) {
      const float* hp = Hd1 + (size_t)(s0 + m * 16 + col) * R_ + kk * 32 + quad * 8;
      float4 v0 = *(const float4*)hp;
      float4 v1 = *(const float4*)(hp + 4);
      bf16x8 a = cvt8(v0, v1);
#pragma unroll
      for (int nl = 0; nl < 4; nl++)
        acc3[m][nl] = MFMA(a, b[nl], acc3[m][nl]);
    }
  }
  float bias[4];
#pragma unroll
  for (int nl = 0; nl < 4; nl++)
    bias[nl] = dbias[(size_t)e * DH_ + d0 + (wv * 4 + nl) * 16 + col];
#pragma unroll
  for (int m = 0; m < 4; m++)
#pragma unroll
    for (int r = 0; r < 4; r++) {
      int t = tok[s0 + m * 16 + quad * 4 + r];
      if (t < 0) continue;
#pragma unroll
      for (int nl = 0; nl < 4; nl++) {
        int d = d0 + (wv * 4 + nl) * 16 + col;
        out[(size_t)t * DH_ + d] = acc3[m][nl][r] + bias[nl];
      }
    }
}

extern "C" void kernel_launch(void* const* d_in, const int* in_sizes, int n_in,
                              void* d_out, int out_size, void* d_ws, size_t ws_size,
                              hipStream_t stream)
{
  (void)in_sizes; (void)n_in; (void)out_size; (void)ws_size;
  const float* x     = (const float*)d_in[0];
  const int*   idx   = (const int*)d_in[1];
  const float* gA    = (const float*)d_in[2];
  const float* gC    = (const float*)d_in[3];
  const float* gBw   = (const float*)d_in[4];
  const float* uA    = (const float*)d_in[5];
  const float* uC    = (const float*)d_in[6];
  const float* uBw   = (const float*)d_in[7];
  const float* dA    = (const float*)d_in[8];
  const float* dC    = (const float*)d_in[9];
  const float* dBw   = (const float*)d_in[10];
  const float* dbias = (const float*)d_in[11];
  float* out = (float*)d_out;

  char* ws = (char*)d_ws;
  int* off = (int*)ws;                          // 9 ints
  int* tok = (int*)(ws + 512);                  // 4608 ints       -> 18944
  float* Hd1 = (float*)(ws + 32768);            // 4608*128 f32    -> 2392064
  short* Xb  = (short*)(ws + 21266432);         // 4608*2048 bf16  -> 40140800
  short* Hgb = (short*)(ws + 40140800);         // 4608*128 bf16   -> 41320448
  short* Hub = (short*)(ws + 41320448);         //                 -> 42500096
  short* gCAb = (short*)(ws + 42500096);        // 8*128*2048      -> 46694400
  short* uCAb = (short*)(ws + 46694400);        //                 -> 50888704
  short* gBb = (short*)(ws + 50888704);         // 8*5632*128      -> 62423040
  short* uBb = (short*)(ws + 62423040);         //                 -> 73957376
  short* dCAb = (short*)(ws + 73957376);        // 8*128*5632      -> 85491712
  short* dBb = (short*)(ws + 85491712);         // 8*2048*128      -> 89686016

  hipMemsetAsync(Hd1, 0, (size_t)TPMAX_ * R_ * sizeof(float), stream);

  k_mega  <<<dim3(MEGA_GRID_), 256, 0, stream>>>(gBw, uBw, dBw, gC, uC, dC,
                                                 gA, uA, dA,
                                                 gBb, uBb, dBb, gCAb, uCAb, dCAb,
                                                 idx, off, tok);
  k_gather<<<dim3(TPMAX_), 256, 0, stream>>>(x, tok, Xb);
  k_stage1<<<dim3(NT_, 2, 2), 256, 0, stream>>>(Xb, gCAb, uCAb, off, Hgb, Hub);
  k_stage2<<<dim3(NT_, 11), 256, 0, stream>>>(Hgb, Hub, gBb, uBb, dCAb, off, Hd1);
  k_stage3<<<dim3(NT_, 8), 256, 0, stream>>>(Hd1, dBb, dbias, off, tok, out);
}

// Round 10
// 333.059 us; speedup vs baseline: 1.0728x; 1.0728x over previous
//
#include <hip/hip_runtime.h>
#include <hip/hip_bf16.h>

#define E_  8
#define T_  4096
#define DH_ 2048
#define DI_ 5632
#define R_  128
#define TILE_ 64
#define NT_ 72                  // T/64 + E  (worst-case padded tiles)
#define TPMAX_ (NT_*TILE_)      // 4608

// k_mega block layout
#define CVT_BLOCKS_ 13312       // 13,631,488 floats (gB+uB+dB) / 1024
#define FOLD_BLOCKS_ 608        // 76 chunks x 8 experts
#define ROUTE_BLK_ (CVT_BLOCKS_ + FOLD_BLOCKS_)   // 13920
#define MEGA_GRID_ (ROUTE_BLK_ + 1)               // 13921

typedef short bf16x8 __attribute__((ext_vector_type(8)));
typedef short bf16x4 __attribute__((ext_vector_type(4)));
typedef float f32x4 __attribute__((ext_vector_type(4)));

#define MFMA(a, b, c) __builtin_amdgcn_mfma_f32_16x16x32_bf16((a), (b), (c), 0, 0, 0)

// LDS-only barrier: orders DS ops (lgkmcnt) without draining in-flight global
// loads (vmcnt). stage2's only cross-wave state is LDS. (T4 discipline.)
#define BAR_LDS() asm volatile("s_waitcnt lgkmcnt(0)\n\ts_barrier" ::: "memory")

__device__ __forceinline__ unsigned short f2bf(float f) {
  union { float f; unsigned u; } v; v.f = f;
  return (unsigned short)((v.u + 0x7fffu + ((v.u >> 16) & 1u)) >> 16);
}

__device__ __forceinline__ bf16x8 cvt8(float4 a, float4 b) {
  bf16x8 o;
  o[0] = (short)f2bf(a.x); o[1] = (short)f2bf(a.y);
  o[2] = (short)f2bf(a.z); o[3] = (short)f2bf(a.w);
  o[4] = (short)f2bf(b.x); o[5] = (short)f2bf(b.y);
  o[6] = (short)f2bf(b.z); o[7] = (short)f2bf(b.w);
  return o;
}

__device__ __forceinline__ int tile_expert(int s0, const int* off) {
  int e = 0;
#pragma unroll
  for (int q = 1; q < E_; q++) if (s0 >= off[q]) e = q;
  return e;
}

// XCD-chunked tile swizzle (locality only, no correctness dependence).
// gridDim.x == NT_ == 72 == 8*9 and linear id = bx + 72*k, so XCD = bx%8:
// each XCD owns 9 contiguous tiles -> ~one expert's weight panel per XCD L2.
// Proven: stage2 FETCH 137.6 MB -> 30.0 MB.
__device__ __forceinline__ int tile_remap(int bx) {
  return (bx & 7) * (NT_ / 8) + (bx >> 3);
}

// ---- MEGA kernel: [cvt B-matrices] + [fold C into A] + [route] in ONE launch.
__global__ __launch_bounds__(256) void k_mega(
    const float* __restrict__ gB, const float* __restrict__ uB,
    const float* __restrict__ dB,
    const float* __restrict__ gC, const float* __restrict__ uC,
    const float* __restrict__ dC,
    const float* __restrict__ gA, const float* __restrict__ uA,
    const float* __restrict__ dA,
    short* __restrict__ gBb, short* __restrict__ uBb, short* __restrict__ dBb,
    short* __restrict__ gCAb, short* __restrict__ uCAb, short* __restrict__ dCAb,
    const int* __restrict__ idx, int* __restrict__ off, int* __restrict__ tok)
{
  const int blk = blockIdx.x;
  const int tid = threadIdx.x;

  if (blk < CVT_BLOCKS_) {   // ---- B-matrix fp32 -> bf16
    long i = (long)(blk * 256 + tid) * 4;
    const float* s; short* d;
    if      (i <  5767168) { s = gB; d = gBb; }
    else if (i < 11534336) { s = uB; d = uBb; i -= 5767168; }
    else                   { s = dB; d = dBb; i -= 11534336; }
    float4 v = *(const float4*)(s + i);
    bf16x4 o;
    o[0] = (short)f2bf(v.x); o[1] = (short)f2bf(v.y);
    o[2] = (short)f2bf(v.z); o[3] = (short)f2bf(v.w);
    *(bf16x4*)(d + i) = o;
    return;
  }

  if (blk == ROUTE_BLK_) {   // ---- routing: prefill tok=-1, count, offsets, scatter
    __shared__ int cnt_[E_], cur_[E_], offs_[E_ + 1];
    for (int p = tid; p < TPMAX_; p += 256) tok[p] = -1;
    if (tid < E_) cnt_[tid] = 0;
    __syncthreads();
    for (int t = tid; t < T_; t += 256) atomicAdd(&cnt_[idx[t]], 1);
    __syncthreads();
    if (tid == 0) {
      int a = 0;
      for (int e = 0; e < E_; e++) {
        offs_[e] = a; cur_[e] = a;
        a += ((cnt_[e] + TILE_ - 1) / TILE_) * TILE_;
      }
      offs_[E_] = a;
    }
    __syncthreads();
    if (tid <= E_) off[tid] = offs_[tid];
    for (int t = tid; t < T_; t += 256) {
      int p = atomicAdd(&cur_[idx[t]], 1);
      tok[p] = t;
    }
    return;
  }

  // ---- fold: CA_e = C @ A_e, bf16 out, same layout as A.
  const int f = blk - CVT_BLOCKS_;
  const int e = f / 76;
  const int c = f % 76;
  const float* A; const float* C; short* O; int D, d0;
  if (c < 16)      { A = gA + (size_t)e * R_ * DH_; C = gC; O = gCAb + (size_t)e * R_ * DH_; D = DH_; d0 = c * 128; }
  else if (c < 32) { A = uA + (size_t)e * R_ * DH_; C = uC; O = uCAb + (size_t)e * R_ * DH_; D = DH_; d0 = (c - 16) * 128; }
  else             { A = dA + (size_t)e * R_ * DI_; C = dC; O = dCAb + (size_t)e * R_ * DI_; D = DI_; d0 = (c - 32) * 128; }

  __shared__ short ATs[128][136];   // ATs[d_local][r] = A[r][d0+d_local] (bf16)
  {
    const int s = tid >> 1, h = (tid & 1) * 64;
    const float* ap = A + (size_t)s * D + d0 + h;
#pragma unroll
    for (int q = 0; q < 16; q++) {
      float4 v = *(const float4*)(ap + q * 4);
      ATs[h + q * 4 + 0][s] = (short)f2bf(v.x);
      ATs[h + q * 4 + 1][s] = (short)f2bf(v.y);
      ATs[h + q * 4 + 2][s] = (short)f2bf(v.z);
      ATs[h + q * 4 + 3][s] = (short)f2bf(v.w);
    }
  }
  __syncthreads();

  const int lane = tid & 63, wv = tid >> 6;
  const int col = lane & 15, quad = lane >> 4;
  f32x4 acc[8][2] = {};
#pragma unroll
  for (int kk = 0; kk < 4; kk++) {
    bf16x8 b[2];
#pragma unroll
    for (int nl = 0; nl < 2; nl++)
      b[nl] = *(const bf16x8*)&ATs[(wv * 2 + nl) * 16 + col][kk * 32 + quad * 8];
#pragma unroll
    for (int m = 0; m < 8; m++) {
      const float* cp = C + (size_t)(m * 16 + col) * R_ + kk * 32 + quad * 8;
      float4 c0 = *(const float4*)cp;
      float4 c1 = *(const float4*)(cp + 4);
      bf16x8 a = cvt8(c0, c1);
      acc[m][0] = MFMA(a, b[0], acc[m][0]);
      acc[m][1] = MFMA(a, b[1], acc[m][1]);
    }
  }
#pragma unroll
  for (int m = 0; m < 8; m++)
#pragma unroll
    for (int nl = 0; nl < 2; nl++)
#pragma unroll
      for (int r = 0; r < 4; r++)
        O[(size_t)(m * 16 + quad * 4 + r) * D + d0 + (wv * 2 + nl) * 16 + col] =
            (short)f2bf(acc[m][nl][r]);
}

// Gather x rows into tile order, fp32 -> bf16 (zeros for pad rows)
__global__ __launch_bounds__(256) void k_gather(
    const float* __restrict__ x, const int* __restrict__ tok,
    short* __restrict__ Xb)
{
  const int p = blockIdx.x;
  const int t = tok[p];
  const int c = threadIdx.x * 8;
  bf16x8 o;
  if (t >= 0) {
    float4 v0 = *(const float4*)(x + (size_t)t * DH_ + c);
    float4 v1 = *(const float4*)(x + (size_t)t * DH_ + c + 4);
    o = cvt8(v0, v1);
  } else {
    o = (bf16x8){0, 0, 0, 0, 0, 0, 0, 0};
  }
  *(bf16x8*)(Xb + (size_t)p * DH_ + c) = o;
}

// Stage 1 (wave-split-K, in-block LDS reduce): Hg/Hu = Xb @ CA_e^T, bf16 out.
// Grid (NT_, 2y, 4 col-quarters) = 576 blocks (2.25/CU — R9's 288 was the
// regression). Block = 64 tokens x 32 R-cols; wave wv computes K-chunk
// wv*512..+512 with the R3-proven acc[4][2] shape (8 MFMA chains), then the
// 4 kc-partials are summed through LDS (kc order == R3's stage1b sum order).
// No Hp round-trip, no stage1b, no global atomics.
__global__ __launch_bounds__(256) void k_stage1(
    const short* __restrict__ Xb,
    const short* __restrict__ gCAb, const short* __restrict__ uCAb,
    const int* __restrict__ off,
    short* __restrict__ Hgb, short* __restrict__ Hub)
{
  const int s0 = tile_remap(blockIdx.x) * TILE_;
  if (s0 >= off[E_]) return;
  const int e = tile_expert(s0, off);
  const int y = blockIdx.y, ns = blockIdx.z;
  const short* CA = (y ? uCAb : gCAb) + (size_t)e * R_ * DH_;
  short* H = y ? Hub : Hgb;

  const int tid = threadIdx.x;
  const int lane = tid & 63, wv = tid >> 6;   // wv = K-chunk index
  const int col = lane & 15, quad = lane >> 4;

  const short* xb = Xb + (size_t)(s0 + col) * DH_ + wv * 512 + quad * 8;
  const short* cb = CA + (size_t)(ns * 32 + col) * DH_ + wv * 512 + quad * 8;

  f32x4 acc[4][2] = {};
#pragma unroll 4
  for (int k0 = 0; k0 < 512; k0 += 32) {
    bf16x8 b0 = *(const bf16x8*)(cb + k0);
    bf16x8 b1 = *(const bf16x8*)(cb + (size_t)16 * DH_ + k0);
#pragma unroll
    for (int m = 0; m < 4; m++) {
      bf16x8 a = *(const bf16x8*)(xb + (size_t)m * 16 * DH_ + k0);
      acc[m][0] = MFMA(a, b0, acc[m][0]);
      acc[m][1] = MFMA(a, b1, acc[m][1]);
    }
  }

  // in-block reduction of the 4 K-chunk partials via LDS ([64][33] pad: ~2-way)
  __shared__ float red[4][64][33];
#pragma unroll
  for (int m = 0; m < 4; m++)
#pragma unroll
    for (int nl = 0; nl < 2; nl++)
#pragma unroll
      for (int r = 0; r < 4; r++)
        red[wv][m * 16 + quad * 4 + r][nl * 16 + col] = acc[m][nl][r];
  __syncthreads();
  {
    const int row = tid >> 2, c0 = (tid & 3) * 8;
    bf16x8 o;
#pragma unroll
    for (int j = 0; j < 8; j++) {
      float s = red[0][row][c0 + j] + red[1][row][c0 + j] +
                red[2][row][c0 + j] + red[3][row][c0 + j];
      o[j] = (short)f2bf(s);
    }
    *(bf16x8*)(H + (size_t)(s0 + row) * R_ + ns * 32 + c0) = o;
  }
}

// Stage 2 (64-token tiles): G/U B-proj, silu-mul, down-CA partial accumulate.
// bf16 LDS staging (proven fast); LDS-only barriers; rcp silu; setprio.
__global__ __launch_bounds__(256) void k_stage2(
    const short* __restrict__ Hgb, const short* __restrict__ Hub,
    const short* __restrict__ gBb, const short* __restrict__ uBb,
    const short* __restrict__ dCAb,
    const int* __restrict__ off, float* __restrict__ Hd1)
{
  const int s0 = tile_remap(blockIdx.x) * TILE_;
  if (s0 >= off[E_]) return;
  const int e = tile_expert(s0, off);
  const int i0 = blockIdx.y * 512;
  const short* Bg = gBb + (size_t)e * DI_ * R_;
  const short* Bu = uBb + (size_t)e * DI_ * R_;
  const short* Ad = dCAb + (size_t)e * R_ * DI_;

  __shared__ short hgs[64][136];
  __shared__ short hus[64][136];
  __shared__ short ZT[64][136];

  const int tid = threadIdx.x;
  const int lane = tid & 63, wv = tid >> 6;
  const int col = lane & 15, quad = lane >> 4;

  // stage Hg/Hu tile into LDS (4 threads/row, 32 shorts each)
  {
    const int row = tid >> 2, seg = (tid & 3) * 32;
    const short* pg = Hgb + (size_t)(s0 + row) * R_ + seg;
    const short* pu = Hub + (size_t)(s0 + row) * R_ + seg;
#pragma unroll
    for (int q = 0; q < 4; q++) {
      *(bf16x8*)&hgs[row][seg + q * 8] = *(const bf16x8*)(pg + q * 8);
      *(bf16x8*)&hus[row][seg + q * 8] = *(const bf16x8*)(pu + q * 8);
    }
  }
  BAR_LDS();   // hgs/hus ds_writes visible; global loads unaffected

  f32x4 dacc[4][2] = {};

  for (int sc = 0; sc < 4; sc++) {
    const int ib = i0 + sc * 128;
    f32x4 gacc[4][2] = {}, uacc[4][2] = {};
    __builtin_amdgcn_s_setprio(1);
#pragma unroll
    for (int kk = 0; kk < 4; kk++) {
      bf16x8 bg[2], bu[2];
#pragma unroll
      for (int nl = 0; nl < 2; nl++) {
        size_t bo = (size_t)(ib + (wv * 2 + nl) * 16 + col) * R_ + kk * 32 + quad * 8;
        bg[nl] = *(const bf16x8*)(Bg + bo);
        bu[nl] = *(const bf16x8*)(Bu + bo);
      }
#pragma unroll
      for (int m = 0; m < 4; m++) {
        bf16x8 ag = *(const bf16x8*)&hgs[m * 16 + col][kk * 32 + quad * 8];
        bf16x8 au = *(const bf16x8*)&hus[m * 16 + col][kk * 32 + quad * 8];
#pragma unroll
        for (int nl = 0; nl < 2; nl++) {
          gacc[m][nl] = MFMA(ag, bg[nl], gacc[m][nl]);
          uacc[m][nl] = MFMA(au, bu[nl], uacc[m][nl]);
        }
      }
    }
    __builtin_amdgcn_s_setprio(0);
    BAR_LDS();   // previous sub-chunk's ZT ds_reads complete (WAR)
#pragma unroll
    for (int m = 0; m < 4; m++)
#pragma unroll
      for (int nl = 0; nl < 2; nl++)
#pragma unroll
        for (int r = 0; r < 4; r++) {
          float g = gacc[m][nl][r];
          float z = g * __builtin_amdgcn_rcpf(1.0f + __expf(-g)) * uacc[m][nl][r];
          ZT[m * 16 + quad * 4 + r][(wv * 2 + nl) * 16 + col] = (short)f2bf(z);
        }
    BAR_LDS();   // ZT ds_writes visible (RAW)
    __builtin_amdgcn_s_setprio(1);
#pragma unroll
    for (int kk2 = 0; kk2 < 4; kk2++) {
      bf16x8 ba[2];
#pragma unroll
      for (int nl = 0; nl < 2; nl++)
        ba[nl] = *(const bf16x8*)(Ad + (size_t)((wv * 2 + nl) * 16 + col) * DI_ +
                                  ib + kk2 * 32 + quad * 8);
#pragma unroll
      for (int m = 0; m < 4; m++) {
        bf16x8 za = *(const bf16x8*)&ZT[m * 16 + col][kk2 * 32 + quad * 8];
        dacc[m][0] = MFMA(za, ba[0], dacc[m][0]);
        dacc[m][1] = MFMA(za, ba[1], dacc[m][1]);
      }
    }
    __builtin_amdgcn_s_setprio(0);
  }
#pragma unroll
  for (int m = 0; m < 4; m++)
#pragma unroll
    for (int nl = 0; nl < 2; nl++)
#pragma unroll
      for (int r = 0; r < 4; r++)
        atomicAdd(&Hd1[(size_t)(s0 + m * 16 + quad * 4 + r) * R_ + (wv * 2 + nl) * 16 + col],
                  dacc[m][nl][r]);
}

// Stage 3 (single phase): out = cvt_bf16(Hd1) @ dB^T + bias.
__global__ __launch_bounds__(256) void k_stage3(
    const float* __restrict__ Hd1,
    const short* __restrict__ dBb, const float* __restrict__ dbias,
    const int* __restrict__ off, const int* __restrict__ tok,
    float* __restrict__ out)
{
  const int s0 = tile_remap(blockIdx.x) * TILE_;
  if (s0 >= off[E_]) return;
  const int e = tile_expert(s0, off);
  const int d0 = blockIdx.y * 256;

  const int tid = threadIdx.x;
  const int lane = tid & 63, wv = tid >> 6;
  const int col = lane & 15, quad = lane >> 4;

  f32x4 acc3[4][4] = {};
#pragma unroll
  for (int kk = 0; kk < 4; kk++) {
    bf16x8 b[4];
#pragma unroll
    for (int nl = 0; nl < 4; nl++)
      b[nl] = *(const bf16x8*)(dBb + (size_t)e * DH_ * R_ +
                               (size_t)(d0 + (wv * 4 + nl) * 16 + col) * R_ +
                               kk * 32 + quad * 8);
#pragma unroll
    for (int m = 0; m < 4; m++) {
      const float* hp = Hd1 + (size_t)(s0 + m * 16 + col) * R_ + kk * 32 + quad * 8;
      float4 v0 = *(const float4*)hp;
      float4 v1 = *(const float4*)(hp + 4);
      bf16x8 a = cvt8(v0, v1);
#pragma unroll
      for (int nl = 0; nl < 4; nl++)
        acc3[m][nl] = MFMA(a, b[nl], acc3[m][nl]);
    }
  }
  float bias[4];
#pragma unroll
  for (int nl = 0; nl < 4; nl++)
    bias[nl] = dbias[(size_t)e * DH_ + d0 + (wv * 4 + nl) * 16 + col];
#pragma unroll
  for (int m = 0; m < 4; m++)
#pragma unroll
    for (int r = 0; r < 4; r++) {
      int t = tok[s0 + m * 16 + quad * 4 + r];
      if (t < 0) continue;
#pragma unroll
      for (int nl = 0; nl < 4; nl++) {
        int d = d0 + (wv * 4 + nl) * 16 + col;
        out[(size_t)t * DH_ + d] = acc3[m][nl][r] + bias[nl];
      }
    }
}

extern "C" void kernel_launch(void* const* d_in, const int* in_sizes, int n_in,
                              void* d_out, int out_size, void* d_ws, size_t ws_size,
                              hipStream_t stream)
{
  (void)in_sizes; (void)n_in; (void)out_size; (void)ws_size;
  const float* x     = (const float*)d_in[0];
  const int*   idx   = (const int*)d_in[1];
  const float* gA    = (const float*)d_in[2];
  const float* gC    = (const float*)d_in[3];
  const float* gBw   = (const float*)d_in[4];
  const float* uA    = (const float*)d_in[5];
  const float* uC    = (const float*)d_in[6];
  const float* uBw   = (const float*)d_in[7];
  const float* dA    = (const float*)d_in[8];
  const float* dC    = (const float*)d_in[9];
  const float* dBw   = (const float*)d_in[10];
  const float* dbias = (const float*)d_in[11];
  float* out = (float*)d_out;

  char* ws = (char*)d_ws;
  int* off = (int*)ws;                          // 9 ints
  int* tok = (int*)(ws + 512);                  // 4608 ints       -> 18944
  float* Hd1 = (float*)(ws + 32768);            // 4608*128 f32    -> 2392064
  short* Xb  = (short*)(ws + 21266432);         // 4608*2048 bf16  -> 40140800
  short* Hgb = (short*)(ws + 40140800);         // 4608*128 bf16   -> 41320448
  short* Hub = (short*)(ws + 41320448);         //                 -> 42500096
  short* gCAb = (short*)(ws + 42500096);        // 8*128*2048      -> 46694400
  short* uCAb = (short*)(ws + 46694400);        //                 -> 50888704
  short* gBb = (short*)(ws + 50888704);         // 8*5632*128      -> 62423040
  short* uBb = (short*)(ws + 62423040);         //                 -> 73957376
  short* dCAb = (short*)(ws + 73957376);        // 8*128*5632      -> 85491712
  short* dBb = (short*)(ws + 85491712);         // 8*2048*128      -> 89686016

  hipMemsetAsync(Hd1, 0, (size_t)TPMAX_ * R_ * sizeof(float), stream);

  k_mega  <<<dim3(MEGA_GRID_), 256, 0, stream>>>(gBw, uBw, dBw, gC, uC, dC,
                                                 gA, uA, dA,
                                                 gBb, uBb, dBb, gCAb, uCAb, dCAb,
                                                 idx, off, tok);
  k_gather<<<dim3(TPMAX_), 256, 0, stream>>>(x, tok, Xb);
  k_stage1<<<dim3(NT_, 2, 4), 256, 0, stream>>>(Xb, gCAb, uCAb, off, Hgb, Hub);
  k_stage2<<<dim3(NT_, 11), 256, 0, stream>>>(Hgb, Hub, gBb, uBb, dCAb, off, Hd1);
  k_stage3<<<dim3(NT_, 8), 256, 0, stream>>>(Hd1, dBb, dbias, off, tok, out);
}